// Round 1
// baseline (230.323 us; speedup 1.0000x reference)
//
#include <hip/hip_runtime.h>
#include <math.h>

// Problem constants
#define N_    4
#define CIN   16
#define COUT  32
#define DD    16
#define HH_   64
#define WW_   64
// per-channel element count for BN: 4*16*64*64
#define MCNT  262144.0f

// ws layout (floats):
// [0, 13824)      wproc[cin][27][cout]   (cout-contiguous for float4 loads)
// [13824, 13856)  sums[32]
// [13856, 13888)  sumsqs[32]
// [13888, 13920)  scale[32]
// [13920, 13952)  shift[32]
#define WS_W      0
#define WS_SUM    13824
#define WS_SUMSQ  13856
#define WS_SCALE  13888
#define WS_SHIFT  13920

// ---------------- Kernel A: weight preprocessing + zero stats ----------------
__global__ void prep_weights(const float* __restrict__ weight, float* __restrict__ ws) {
    int t = threadIdx.x;  // 512 threads, 1 block
    if (t < 64) ws[WS_SUM + t] = 0.0f;  // zero sums + sumsqs (must happen every call)
    int cout = t >> 4, cin = t & 15;
    const float* wp = weight + (cout * CIN + cin) * 27;
    float wv[27];
    float mx = -INFINITY;
    #pragma unroll
    for (int k = 0; k < 27; ++k) { wv[k] = wp[k]; mx = fmaxf(mx, wv[k]); }
    float cutoff = mx * 0.5f;
    const float win[3] = {0.08f, 1.0f, 0.08f};
    #pragma unroll
    for (int k = 0; k < 27; ++k) {
        float w = wv[k];
        float s = (w > 0.0f) ? 1.0f : ((w < 0.0f) ? -1.0f : 0.0f);
        float shr = s * fmaxf(fabsf(w) - cutoff * 0.01f, 0.0f);
        float o = (w < cutoff) ? shr : w;
        int kd = k / 9, kr = k % 9, kh = kr / 3, kw = kr % 3;
        o *= win[kd] * win[kh] * win[kw];
        ws[WS_W + (cin * 27 + k) * COUT + cout] = o;
    }
}

// ---------------- Kernel B: conv3d + bias + partial BN stats ----------------
// Block tile: one (n, d), 8 h-rows, all 64 w, all 32 couts.
// Thread (256/blk): wg = t&15 -> w0 = 4*wg; hg = (t>>4)&1 -> hb = 4*hg; cg = t>>5 -> c0 = 4*cg
// Each thread: acc[4 couts][4 h][4 w]
#define RS 76  // xs row stride (floats), padded for alignment
__global__ __launch_bounds__(256, 2)
void conv_kernel(const float* __restrict__ x, const float* __restrict__ bias,
                 const float* __restrict__ wsw, float* __restrict__ out,
                 float* __restrict__ sums, float* __restrict__ sumsqs) {
    __shared__ float wlds[CIN * 27 * COUT];  // 13824 floats = 55296 B
    __shared__ float xs[3 * 10 * RS];        // 2280 floats  =  9120 B

    int b = blockIdx.x;            // 512 blocks: n(4) x d(16) x ht(8)
    int n  = b >> 7;
    int d  = (b >> 3) & 15;
    int h0 = (b & 7) * 8;
    int tid = threadIdx.x;

    // stage weights once
    for (int i = tid; i < CIN * 27 * COUT; i += 256) wlds[i] = wsw[i];

    int wg = tid & 15, hg = (tid >> 4) & 1, cg = tid >> 5;
    int w0 = wg * 4, hb = hg * 4, c0 = cg * 4;

    float acc[4][4][4];
    #pragma unroll
    for (int c = 0; c < 4; ++c)
        #pragma unroll
        for (int i = 0; i < 4; ++i)
            #pragma unroll
            for (int j = 0; j < 4; ++j) acc[c][i][j] = 0.0f;

    const float* xn = x + (size_t)n * CIN * DD * HH_ * WW_;

    for (int cin = 0; cin < CIN; ++cin) {
        __syncthreads();  // protect xs from previous iteration (also fences wlds on iter 0)
        const float* xc = xn + cin * DD * HH_ * WW_;
        for (int idx = tid; idx < 3 * 10 * RS; idx += 256) {
            int row = idx / RS, c = idx - row * RS;
            int zd = d - 1 + row / 10;
            int zh = h0 - 1 + (row % 10);
            int w = c - 4;  // element index c holds input column w = c-4; valid reads use c in [3,68]
            float v = 0.0f;
            if ((unsigned)zd < DD && (unsigned)zh < HH_ && (unsigned)w < WW_)
                v = xc[(zd * HH_ + zh) * WW_ + w];
            xs[idx] = v;
        }
        __syncthreads();

        const float* wc = &wlds[cin * 27 * COUT];
        for (int kd = 0; kd < 3; ++kd) {
            const float* xp = &xs[kd * 10 * RS];
            float4 wv[9];
            #pragma unroll
            for (int j = 0; j < 9; ++j)
                wv[j] = *(const float4*)&wc[(kd * 9 + j) * COUT + c0];
            #pragma unroll
            for (int rr = 0; rr < 6; ++rr) {
                const float* xr_ = &xp[(hb + rr) * RS + w0];
                float  xl = xr_[3];
                float4 xm = *(const float4*)&xr_[4];
                float  xrr = xr_[8];
                float xv[6] = {xl, xm.x, xm.y, xm.z, xm.w, xrr};
                #pragma unroll
                for (int kh = 0; kh < 3; ++kh) {
                    int hh = rr - kh;
                    if (hh < 0 || hh > 3) continue;  // compile-time pruned
                    #pragma unroll
                    for (int kw = 0; kw < 3; ++kw) {
                        float4 w4 = wv[kh * 3 + kw];
                        #pragma unroll
                        for (int t2 = 0; t2 < 4; ++t2) {
                            float xx = xv[t2 + kw];
                            acc[0][hh][t2] = fmaf(w4.x, xx, acc[0][hh][t2]);
                            acc[1][hh][t2] = fmaf(w4.y, xx, acc[1][hh][t2]);
                            acc[2][hh][t2] = fmaf(w4.z, xx, acc[2][hh][t2]);
                            acc[3][hh][t2] = fmaf(w4.w, xx, acc[3][hh][t2]);
                        }
                    }
                }
            }
        }
    }

    // bias + store y + per-channel partial stats
    float s1[4], s2[4];
    #pragma unroll
    for (int c = 0; c < 4; ++c) {
        float bval = bias[c0 + c];
        s1[c] = 0.0f; s2[c] = 0.0f;
        #pragma unroll
        for (int i = 0; i < 4; ++i) {
            float4 o;
            float* op = (float*)&o;
            #pragma unroll
            for (int j = 0; j < 4; ++j) {
                float v = acc[c][i][j] + bval;
                op[j] = v;
                s1[c] += v;
                s2[c] += v * v;
            }
            int h = h0 + hb + i;
            *(float4*)&out[((((size_t)n * COUT + c0 + c) * DD + d) * HH_ + h) * WW_ + w0] = o;
        }
    }
    // reduce across the 32 threads sharing each cout (lanes t&31 within wave halves)
    #pragma unroll
    for (int m = 1; m < 32; m <<= 1) {
        #pragma unroll
        for (int c = 0; c < 4; ++c) {
            s1[c] += __shfl_xor(s1[c], m);
            s2[c] += __shfl_xor(s2[c], m);
        }
    }
    if ((tid & 31) == 0) {
        #pragma unroll
        for (int c = 0; c < 4; ++c) {
            atomicAdd(&sums[c0 + c], s1[c]);
            atomicAdd(&sumsqs[c0 + c], s2[c]);
        }
    }
}

// ---------------- Kernel C: finalize BN scale/shift ----------------
__global__ void stats_kernel(const float* __restrict__ gamma, const float* __restrict__ beta,
                             float* __restrict__ ws) {
    int c = threadIdx.x;
    if (c >= 32) return;
    float mean = ws[WS_SUM + c] / MCNT;
    float var  = ws[WS_SUMSQ + c] / MCNT - mean * mean;
    float rstd = rsqrtf(var + 1e-5f);
    float sc = gamma[c] * rstd;
    ws[WS_SCALE + c] = sc;
    ws[WS_SHIFT + c] = beta[c] - mean * sc;
}

// ---------------- Kernel D: BN apply + softplus (in place on d_out) ----------------
__global__ void bn_act_kernel(float* __restrict__ out, const float* __restrict__ ws) {
    const int NV4 = (N_ * COUT * DD * HH_ * WW_) / 4;  // 2097152 float4s; 16384 per (n,c)
    int stride = gridDim.x * blockDim.x;
    float4* o4 = (float4*)out;
    for (int i = blockIdx.x * blockDim.x + threadIdx.x; i < NV4; i += stride) {
        int ch = (i >> 14) & 31;
        float sc = ws[WS_SCALE + ch];
        float sh = ws[WS_SHIFT + ch];
        float4 v = o4[i];
        float* vp = (float*)&v;
        #pragma unroll
        for (int j = 0; j < 4; ++j) {
            float z = vp[j] * sc + sh;
            // softplus = logaddexp(z, 0) = max(z,0) + log1p(exp(-|z|))
            vp[j] = fmaxf(z, 0.0f) + log1pf(expf(-fabsf(z)));
        }
        o4[i] = v;
    }
}

extern "C" void kernel_launch(void* const* d_in, const int* in_sizes, int n_in,
                              void* d_out, int out_size, void* d_ws, size_t ws_size,
                              hipStream_t stream) {
    const float* x      = (const float*)d_in[0];
    const float* weight = (const float*)d_in[1];
    const float* bias   = (const float*)d_in[2];
    const float* gamma  = (const float*)d_in[3];
    const float* beta   = (const float*)d_in[4];
    float* out = (float*)d_out;
    float* ws  = (float*)d_ws;

    hipLaunchKernelGGL(prep_weights, dim3(1), dim3(512), 0, stream, weight, ws);
    hipLaunchKernelGGL(conv_kernel, dim3(512), dim3(256), 0, stream,
                       x, bias, ws + WS_W, out, ws + WS_SUM, ws + WS_SUMSQ);
    hipLaunchKernelGGL(stats_kernel, dim3(1), dim3(64), 0, stream, gamma, beta, ws);
    hipLaunchKernelGGL(bn_act_kernel, dim3(2048), dim3(256), 0, stream, out, ws);
}

// Round 2
// 153.894 us; speedup vs baseline: 1.4966x; 1.4966x over previous
//
#include <hip/hip_runtime.h>
#include <math.h>

// Problem constants
#define N_    4
#define CIN   16
#define COUT  32
#define DD    16
#define HH_   64
#define WW_   64
#define MCNT  262144.0f   // per-channel count: 4*16*64*64

// ws layout (floats):
// [0, 13824)      wproc[cin][27][cout]   (cout-contiguous)
// [13824, 13856)  sums[32]
// [13856, 13888)  sumsqs[32]
// [13888, 13920)  scale[32]
// [13920, 13952)  shift[32]
#define WS_W      0
#define WS_SUM    13824
#define WS_SUMSQ  13856
#define WS_SCALE  13888
#define WS_SHIFT  13920

// ---------------- Kernel A: weight preprocessing + zero stats ----------------
__global__ void prep_weights(const float* __restrict__ weight, float* __restrict__ ws) {
    int t = threadIdx.x;  // 512 threads, 1 block
    if (t < 64) ws[WS_SUM + t] = 0.0f;  // zero sums + sumsqs every call
    int cout = t >> 4, cin = t & 15;
    const float* wp = weight + (cout * CIN + cin) * 27;
    float wv[27];
    float mx = -INFINITY;
    #pragma unroll
    for (int k = 0; k < 27; ++k) { wv[k] = wp[k]; mx = fmaxf(mx, wv[k]); }
    float cutoff = mx * 0.5f;
    const float win[3] = {0.08f, 1.0f, 0.08f};
    #pragma unroll
    for (int k = 0; k < 27; ++k) {
        float w = wv[k];
        float s = (w > 0.0f) ? 1.0f : ((w < 0.0f) ? -1.0f : 0.0f);
        float shr = s * fmaxf(fabsf(w) - cutoff * 0.01f, 0.0f);
        float o = (w < cutoff) ? shr : w;
        int kd = k / 9, kr = k % 9, kh = kr / 3, kw = kr % 3;
        o *= win[kd] * win[kh] * win[kw];
        ws[WS_W + (cin * 27 + k) * COUT + cout] = o;
    }
}

// ---------------- Kernel B: conv3d + bias + partial BN stats ----------------
// Grid: 1024 blocks = n(4) x d(16) x ht(16 tiles of 4 h-rows).
// Block tile: 32 cout x 4 h x 64 w, 256 threads.
// Wave lanes: wg = tid&15 (w0 = 4*wg), cg = (tid>>4)&3.
// Wave id v = tid>>6: cohalf = v&1 (co0 = cohalf*16 + cg*4), hhalf = v>>1 (rows 2*hhalf..+1).
// => within a wave-instruction ALL lanes read the SAME xs row: cg lanes broadcast
//    (same addr), wg lanes 2-way (free). No LDS bank conflicts.
#define RS 68  // xs row stride in floats; idx c holds x[w = c-1], c in [0,65] valid
__global__ __launch_bounds__(256, 4)
void conv_kernel(const float* __restrict__ x, const float* __restrict__ bias,
                 const float* __restrict__ wsw, float* __restrict__ out,
                 float* __restrict__ sums, float* __restrict__ sumsqs) {
    __shared__ float xs[3 * 6 * RS];   // 4896 B
    __shared__ float sred[16][8];

    int b = blockIdx.x;
    int n  = b >> 8;
    int d  = (b >> 4) & 15;
    int h0 = (b & 15) << 2;
    int tid = threadIdx.x;

    int wg = tid & 15;
    int cg = (tid >> 4) & 3;
    int v  = tid >> 6;
    int cohalf = v & 1;
    int hhalf  = v >> 1;
    int w0 = wg * 4;
    int co0 = cohalf * 16 + cg * 4;

    float acc[4][2][4];
    #pragma unroll
    for (int c = 0; c < 4; ++c)
        #pragma unroll
        for (int i = 0; i < 2; ++i)
            #pragma unroll
            for (int j = 0; j < 4; ++j) acc[c][i][j] = 0.0f;

    const float* xn = x + (size_t)n * CIN * DD * HH_ * WW_;

    for (int cin = 0; cin < CIN; ++cin) {
        __syncthreads();  // protect xs from previous iteration
        const float* xc = xn + cin * DD * HH_ * WW_;
        for (int idx = tid; idx < 3 * 6 * RS; idx += 256) {
            int row = idx / RS;         // 0..17
            int c   = idx - row * RS;   // 0..67
            int dd  = row / 6;
            int r   = row - dd * 6;
            int zd = d - 1 + dd;
            int zh = h0 - 1 + r;
            int w  = c - 1;
            float val = 0.0f;
            if ((unsigned)zd < DD && (unsigned)zh < HH_ && (unsigned)w < WW_)
                val = xc[(zd * HH_ + zh) * WW_ + w];
            xs[idx] = val;
        }
        __syncthreads();

        const float* wc = wsw + cin * 27 * COUT + co0;
        #pragma unroll 1
        for (int kd = 0; kd < 3; ++kd) {
            // weights for this (cin,kd): 9 taps x 4 couts, from L1/L2 (wave-dedup'd)
            float4 wv[9];
            #pragma unroll
            for (int j = 0; j < 9; ++j)
                wv[j] = *(const float4*)&wc[(kd * 9 + j) * COUT];
            const float* xp = &xs[(kd * 6 + hhalf * 2) * RS];
            #pragma unroll
            for (int rr = 0; rr < 4; ++rr) {
                const float* xr_ = &xp[rr * RS + w0];
                float4 xm = *(const float4*)xr_;   // x[w0-1 .. w0+2]
                float x4 = xr_[4];                 // x[w0+3]
                float x5 = xr_[5];                 // x[w0+4]
                float xv[6] = {xm.x, xm.y, xm.z, xm.w, x4, x5};
                #pragma unroll
                for (int kh = 0; kh < 3; ++kh) {
                    int i = rr - kh;
                    if (i < 0 || i > 1) continue;  // compile-time pruned
                    #pragma unroll
                    for (int kw = 0; kw < 3; ++kw) {
                        float4 w4 = wv[kh * 3 + kw];
                        #pragma unroll
                        for (int j = 0; j < 4; ++j) {
                            float xx = xv[j + kw];
                            acc[0][i][j] = fmaf(w4.x, xx, acc[0][i][j]);
                            acc[1][i][j] = fmaf(w4.y, xx, acc[1][i][j]);
                            acc[2][i][j] = fmaf(w4.z, xx, acc[2][i][j]);
                            acc[3][i][j] = fmaf(w4.w, xx, acc[3][i][j]);
                        }
                    }
                }
            }
        }
    }

    // bias + store y + per-channel partial stats
    float s1[4], s2[4];
    #pragma unroll
    for (int c = 0; c < 4; ++c) {
        float bval = bias[co0 + c];
        s1[c] = 0.0f; s2[c] = 0.0f;
        #pragma unroll
        for (int i = 0; i < 2; ++i) {
            float4 o;
            float* op = (float*)&o;
            #pragma unroll
            for (int j = 0; j < 4; ++j) {
                float val = acc[c][i][j] + bval;
                op[j] = val;
                s1[c] += val;
                s2[c] += val * val;
            }
            int h = h0 + hhalf * 2 + i;
            *(float4*)&out[((((size_t)n * COUT + co0 + c) * DD + d) * HH_ + h) * WW_ + w0] = o;
        }
    }
    // reduce across the 16 wg lanes sharing each (cg, cohalf, hhalf)
    #pragma unroll
    for (int m = 1; m < 16; m <<= 1) {
        #pragma unroll
        for (int c = 0; c < 4; ++c) {
            s1[c] += __shfl_xor(s1[c], m);
            s2[c] += __shfl_xor(s2[c], m);
        }
    }
    if ((tid & 15) == 0) {
        int g = tid >> 4;  // cg + 4*v
        #pragma unroll
        for (int c = 0; c < 4; ++c) { sred[g][c] = s1[c]; sred[g][4 + c] = s2[c]; }
    }
    __syncthreads();
    if (tid < 64) {
        int co   = tid & 31;
        int kind = tid >> 5;
        int ch   = (co >> 4) & 1;   // cohalf
        int cgg  = (co >> 2) & 3;
        int c    = co & 3;
        float val = sred[ch * 4 + cgg][kind * 4 + c] + sred[(ch + 2) * 4 + cgg][kind * 4 + c];
        atomicAdd(kind ? &sumsqs[co] : &sums[co], val);
    }
}

// ---------------- Kernel C: finalize BN scale/shift ----------------
__global__ void stats_kernel(const float* __restrict__ gamma, const float* __restrict__ beta,
                             float* __restrict__ ws) {
    int c = threadIdx.x;
    if (c >= 32) return;
    float mean = ws[WS_SUM + c] / MCNT;
    float var  = ws[WS_SUMSQ + c] / MCNT - mean * mean;
    float rstd = rsqrtf(var + 1e-5f);
    float sc = gamma[c] * rstd;
    ws[WS_SCALE + c] = sc;
    ws[WS_SHIFT + c] = beta[c] - mean * sc;
}

// ---------------- Kernel D: BN apply + softplus (in place on d_out) ----------------
__global__ void bn_act_kernel(float* __restrict__ out, const float* __restrict__ ws) {
    const int NV4 = (N_ * COUT * DD * HH_ * WW_) / 4;  // 16384 float4 per (n,c)
    int stride = gridDim.x * blockDim.x;
    float4* o4 = (float4*)out;
    for (int i = blockIdx.x * blockDim.x + threadIdx.x; i < NV4; i += stride) {
        int ch = (i >> 14) & 31;
        float sc = ws[WS_SCALE + ch];
        float sh = ws[WS_SHIFT + ch];
        float4 val = o4[i];
        float* vp = (float*)&val;
        #pragma unroll
        for (int j = 0; j < 4; ++j) {
            float z = vp[j] * sc + sh;
            vp[j] = fmaxf(z, 0.0f) + log1pf(expf(-fabsf(z)));
        }
        o4[i] = val;
    }
}

extern "C" void kernel_launch(void* const* d_in, const int* in_sizes, int n_in,
                              void* d_out, int out_size, void* d_ws, size_t ws_size,
                              hipStream_t stream) {
    const float* x      = (const float*)d_in[0];
    const float* weight = (const float*)d_in[1];
    const float* bias   = (const float*)d_in[2];
    const float* gamma  = (const float*)d_in[3];
    const float* beta   = (const float*)d_in[4];
    float* out = (float*)d_out;
    float* ws  = (float*)d_ws;

    hipLaunchKernelGGL(prep_weights, dim3(1), dim3(512), 0, stream, weight, ws);
    hipLaunchKernelGGL(conv_kernel, dim3(1024), dim3(256), 0, stream,
                       x, bias, ws + WS_W, out, ws + WS_SUM, ws + WS_SUMSQ);
    hipLaunchKernelGGL(stats_kernel, dim3(1), dim3(64), 0, stream, gamma, beta, ws);
    hipLaunchKernelGGL(bn_act_kernel, dim3(2048), dim3(256), 0, stream, out, ws);
}